// Round 9
// baseline (28.856 us; speedup 1.0000x reference)
//
#include <hip/hip_runtime.h>
#include <math.h>

#define N_  4
#define C_  3
#define H_  540
#define W_  960
#define HO_ 1080
#define WO_ 1920

typedef float f32x4 __attribute__((ext_vector_type(4)));
typedef float f32x2 __attribute__((ext_vector_type(2)));

// Thread = (n, c, ly, tx): owns low-res cols [4tx, 4tx+4), output rows {2ly, 2ly+1},
// output cols [8tx, 8tx+8) -> 16 output px, 4 f32x4 stores.
// Window proof: ix(ox) = ox/2 + 0.25 - jx -> x0 in {m-1, m}, m = ox>>1;
//               iy(oy) = oy/2 + 0.25 - jy -> y0 in {ly-1, ly}; z row == ly.
// Clamped window loads make border-excluded 3x3 pools == plain min/max over the
// clamped 3x6 window (duplicates never change min/max).
//
// Ladder: R2 naive-fused 33.2 | R3 +XCD swizzle 30.0 | R5 nt stores 33.7
// (REGRESSED, reverted) | R6 8-col tile 42.0 (REGRESSED - VGPR cliff, reverted)
// | R7 +y-blend-first VALU trim 28.0 | R8 packed-f32 pixel loop 28.0 (NEUTRAL -
// pixel FLOPs fully hidden).
// R9: edge columns via wave shuffle. Lane l-1's m.w IS lane l's cL; lane l+1's
// m.x IS lane l's cR (consecutive lanes = consecutive tx within a row). Image
// edges (tx==0 / tx==TX-1) are the clamp cases (= own m.x / m.w, no load).
// Only wave-boundary lanes need a predicated 1-lane load. VMEM/thread 13 -> 7.
__global__ __launch_bounds__(256) void taa_fused_kernel(
    const float* __restrict__ frame,
    const float* __restrict__ jitter,
    float* __restrict__ out,
    int total_threads, int n_blocks, long long out_elems)
{
    // ---- bijective chunked XCD swizzle (nwg = n_blocks, 8 XCDs)
    int b   = blockIdx.x;
    int q   = n_blocks >> 3, r = n_blocks & 7;
    int xcd = b & 7, i = b >> 3;
    int wb  = (xcd < r ? xcd * (q + 1) : r * (q + 1) + (xcd - r) * q) + i;

    int idx = wb * 256 + threadIdx.x;
    if (idx >= total_threads) return;   // never fires (grid exact); kept as guard

    const int TX = W_ / 4;   // 240
    int tx  = idx % TX;
    int t   = idx / TX;
    int ly  = t % H_;
    int nc  = t / H_;            // n*C_ + c  in [0,12)
    int n   = nc / C_;
    int lx0 = tx * 4;
    int lane = threadIdx.x & 63;

    float jx = jitter[2 * n + 0];
    float jy = jitter[2 * n + 1];
    int jnx = (int)floorf(jx * 2.0f);
    int jny = (int)floorf(jy * 2.0f);
    int bjx = (int)floorf(jitter[0] * 2.0f);   // beta lattice uses batch-0 jitter
    int bjy = (int)floorf(jitter[1] * 2.0f);
    bool zcoin = (jnx == bjx) && (jny == bjy); // z-lattice coincides with beta-lattice

    const float* fp = frame + (size_t)nc * (H_ * W_);

    int r0 = (ly > 0)      ? ly - 1 : 0;
    int r2 = (ly < H_ - 1) ? ly + 1 : H_ - 1;

    const float* rp0 = fp + r0 * W_;
    const float* rp1 = fp + ly * W_;
    const float* rp2 = fp + r2 * W_;

    // ---- 3 aligned float4 loads (the only bulk loads)
    f32x4 m0 = *(const f32x4*)(rp0 + lx0);
    f32x4 m1 = *(const f32x4*)(rp1 + lx0);
    f32x4 m2 = *(const f32x4*)(rp2 + lx0);

    // ---- edge columns from neighbor lanes (LDS pipe, no VMEM)
    float sl0 = __shfl_up((float)m0.w, 1);
    float sl1 = __shfl_up((float)m1.w, 1);
    float sl2 = __shfl_up((float)m2.w, 1);
    float sr0 = __shfl_down((float)m0.x, 1);
    float sr1 = __shfl_down((float)m1.x, 1);
    float sr2 = __shfl_down((float)m2.x, 1);

    // wave-boundary lanes: predicated 1-lane loads
    bool needL = (lane == 0)  && (tx != 0);
    bool needR = (lane == 63) && (tx != TX - 1);
    if (needL) {
        sl0 = rp0[lx0 - 1]; sl1 = rp1[lx0 - 1]; sl2 = rp2[lx0 - 1];
    }
    if (needR) {
        sr0 = rp0[lx0 + 4]; sr1 = rp1[lx0 + 4]; sr2 = rp2[lx0 + 4];
    }

    float w0[6], w1[6], w2[6];
    bool le = (tx == 0), re = (tx == TX - 1);   // image-edge clamp cases
    w0[0] = le ? m0.x : sl0;  w0[1]=m0.x; w0[2]=m0.y; w0[3]=m0.z; w0[4]=m0.w;  w0[5] = re ? m0.w : sr0;
    w1[0] = le ? m1.x : sl1;  w1[1]=m1.x; w1[2]=m1.y; w1[3]=m1.z; w1[4]=m1.w;  w1[5] = re ? m1.w : sr1;
    w2[0] = le ? m2.x : sl2;  w2[1]=m2.x; w2[2]=m2.y; w2[3]=m2.z; w2[4]=m2.w;  w2[5] = re ? m2.w : sr2;

    // ---- 3x3 min/max pools for the 4 low-res cols (column partials first)
    float cmax[6], cmin[6];
    #pragma unroll
    for (int j = 0; j < 6; ++j) {
        cmax[j] = fmaxf(fmaxf(w0[j], w1[j]), w2[j]);
        cmin[j] = fminf(fminf(w0[j], w1[j]), w2[j]);
    }
    float vmax[4], vmin[4];
    #pragma unroll
    for (int p = 0; p < 4; ++p) {
        vmax[p] = fmaxf(fmaxf(cmax[p], cmax[p+1]), cmax[p+2]);
        vmin[p] = fminf(fminf(cmin[p], cmin[p+1]), cmin[p+2]);
    }

    // ---- x-grid constants per output-column parity (exact reference op order)
    float wx_[2]; bool dxm1_[2];
    #pragma unroll
    for (int par = 0; par < 2; ++par) {
        int ox = 8 * tx + par;
        float xs = (2.0f * (float)ox + 1.0f) / (float)WO_ - 1.0f;
        float gx = xs + 2.0f * (0.5f - jx) / (float)W_;
        float ix = ((gx + 1.0f) * (float)W_ - 1.0f) / 2.0f;
        float x0f = floorf(ix);
        wx_[par]   = ix - x0f;
        dxm1_[par] = ((int)x0f < lx0);   // x0 = m-1 (window shift) vs m
    }
    f32x2 wx2 = { wx_[0], wx_[1] };

    size_t base = (size_t)nc * ((size_t)HO_ * WO_);

    #pragma unroll
    for (int ry = 0; ry < 2; ++ry) {
        int oy = 2 * ly + ry;
        float ysv = (2.0f * (float)oy + 1.0f) / (float)HO_ - 1.0f;
        float gy = ysv + 2.0f * (0.5f - jy) / (float)H_;
        float iy = ((gy + 1.0f) * (float)H_ - 1.0f) / 2.0f;
        float y0f = floorf(iy);
        float wy  = iy - y0f;
        bool up = ((int)y0f < ly);   // y0 row = ly-1 (window row0) else ly (row1)

        // y-blend first (wy, up are image-uniform; FP reorder vs ref is ~1 ulp)
        float brow[6];
        #pragma unroll
        for (int j = 0; j < 6; ++j) {
            float t0 = up ? w0[j] : w1[j];
            float t1 = up ? w1[j] : w2[j];
            brow[j] = t0 + wy * (t1 - t0);
        }
        // parity-shifted 5-wide views: s[j] = brow[j + (dm ? 0 : 1)]
        float s0[5], s1[5];
        #pragma unroll
        for (int j = 0; j < 5; ++j) {
            s0[j] = dxm1_[0] ? brow[j] : brow[j + 1];
            s1[j] = dxm1_[1] ? brow[j] : brow[j + 1];
        }

        bool rowb = (ry == bjy);
        float res[8];
        #pragma unroll
        for (int bcol = 0; bcol < 4; ++bcol) {
            // packed pair: parities 0,1 of this bcol -> v_pk_fma / v_pk_min / v_pk_max
            f32x2 v0 = { s0[bcol],     s1[bcol]     };
            f32x2 v1 = { s0[bcol + 1], s1[bcol + 1] };
            f32x2 bil = v0 + wx2 * (v1 - v0);
            f32x2 mx = { vmax[bcol], vmax[bcol] };
            f32x2 mn = { vmin[bcol], vmin[bcol] };
            f32x2 h  = __builtin_elementwise_max(mn, __builtin_elementwise_min(mx, bil));
            float zv = zcoin ? w1[bcol + 1] : 0.0f;
            res[2*bcol + 0] = (rowb && (bjx == 0)) ? (0.1f * zv + (1.0f - 0.1f) * h.x) : h.x;
            res[2*bcol + 1] = (rowb && (bjx == 1)) ? (0.1f * zv + (1.0f - 0.1f) * h.y) : h.y;
        }

        size_t off = base + (size_t)oy * WO_ + (size_t)8 * tx;
        if ((long long)(off + 8) <= out_elems) {   // defensive: never write OOB
            f32x4 lo = { res[0], res[1], res[2], res[3] };
            f32x4 hi = { res[4], res[5], res[6], res[7] };
            *(f32x4*)(out + off)     = lo;
            *(f32x4*)(out + off + 4) = hi;
        }
    }
}

extern "C" void kernel_launch(void* const* d_in, const int* in_sizes, int n_in,
                              void* d_out, int out_size, void* d_ws, size_t ws_size,
                              hipStream_t stream) {
    const float* frame  = (const float*)d_in[0];
    const float* jitter = (const float*)d_in[1];
    float* out = (float*)d_out;

    const int total = N_ * C_ * H_ * (W_ / 4);   // 1,555,200 threads, 16 px each
    const int block = 256;
    const int grid  = (total + block - 1) / block;  // 6075 blocks exactly
    taa_fused_kernel<<<grid, block, 0, stream>>>(frame, jitter, out,
                                                 total, grid, (long long)out_size);
}

// Round 10
// 26.707 us; speedup vs baseline: 1.0804x; 1.0804x over previous
//
#include <hip/hip_runtime.h>
#include <math.h>

#define N_  4
#define C_  3
#define H_  540
#define W_  960
#define HO_ 1080
#define WO_ 1920

typedef float f32x4 __attribute__((ext_vector_type(4)));
typedef float f32x2 __attribute__((ext_vector_type(2)));

// Thread = (n, c, ly2, tx): owns low-res rows {2ly2, 2ly2+1} x cols [4tx,4tx+4)
// -> output rows 4ly2..4ly2+3, cols [8tx, 8tx+8): 32 px, 8 f32x4 stores.
// Needs input rows 2ly2-1 .. 2ly2+2 (4 clamped rows x 6 clamped cols).
// Window proof: ix(ox) = ox/2 + 0.25 - jx -> x0 in {m-1, m}; iy similar; z row == lr.
// Clamped loads make border-excluded 3x3 pools == plain min/max over the window.
//
// Ladder: R2 33.2 | R3 +XCD swizzle 30.0 | R5 nt stores 33.7 (REGR, reverted)
// | R6 8-col x-tile 42.0 (REGR - VGPR cliff) | R7 y-blend-first trim 28.0
// | R8 packed-f32 28.0 (NEUTRAL) | R9 edge shuffles 28.9 (REGR, reverted).
// R10: y-doubled tile - 2 low-res rows/thread: 4 input rows serve 4 output
// rows (read insts -33%/byte, x-constants amortized 2x, waves halved, ILP 2x).
// Live state ~90-110 VGPR, kept below R6's cliff.
__global__ __launch_bounds__(256) void taa_fused_kernel(
    const float* __restrict__ frame,
    const float* __restrict__ jitter,
    float* __restrict__ out,
    int total_threads, int n_blocks, long long out_elems)
{
    // ---- bijective chunked XCD swizzle (nwg = n_blocks, 8 XCDs)
    int b   = blockIdx.x;
    int q   = n_blocks >> 3, r = n_blocks & 7;
    int xcd = b & 7, i = b >> 3;
    int wb  = (xcd < r ? xcd * (q + 1) : r * (q + 1) + (xcd - r) * q) + i;

    int idx = wb * 256 + threadIdx.x;
    if (idx >= total_threads) return;

    const int TX = W_ / 4;   // 240
    const int HY = H_ / 2;   // 270
    int tx  = idx % TX;
    int t   = idx / TX;
    int ly2 = t % HY;
    int nc  = t / HY;            // n*C_ + c  in [0,12)
    int n   = nc / C_;
    int lx0 = tx * 4;
    int ly0 = ly2 * 2;           // first low-res row of the pair

    float jx = jitter[2 * n + 0];
    float jy = jitter[2 * n + 1];
    int jnx = (int)floorf(jx * 2.0f);
    int jny = (int)floorf(jy * 2.0f);
    int bjx = (int)floorf(jitter[0] * 2.0f);   // beta lattice uses batch-0 jitter
    int bjy = (int)floorf(jitter[1] * 2.0f);
    bool zcoin = (jnx == bjx) && (jny == bjy); // z-lattice coincides with beta-lattice

    const float* fp = frame + (size_t)nc * (H_ * W_);

    int rA = (ly0 > 0) ? ly0 - 1 : 0;          // clamped row ly0-1
    int rD = (ly0 + 2 < H_) ? ly0 + 2 : H_ - 1; // clamped row ly0+2
    int cL = (lx0 > 0)      ? lx0 - 1 : 0;
    int cR = (lx0 + 4 < W_) ? lx0 + 4 : W_ - 1;

    // ---- 4x6 clamped window (12 load instructions)
    float w0[6], w1[6], w2[6], w3[6];
    {
        const float* rp = fp + rA * W_;
        f32x4 m = *(const f32x4*)(rp + lx0);
        w0[0]=rp[cL]; w0[1]=m.x; w0[2]=m.y; w0[3]=m.z; w0[4]=m.w; w0[5]=rp[cR];
        rp = fp + ly0 * W_;
        m = *(const f32x4*)(rp + lx0);
        w1[0]=rp[cL]; w1[1]=m.x; w1[2]=m.y; w1[3]=m.z; w1[4]=m.w; w1[5]=rp[cR];
        rp = fp + (ly0 + 1) * W_;
        m = *(const f32x4*)(rp + lx0);
        w2[0]=rp[cL]; w2[1]=m.x; w2[2]=m.y; w2[3]=m.z; w2[4]=m.w; w2[5]=rp[cR];
        rp = fp + rD * W_;
        m = *(const f32x4*)(rp + lx0);
        w3[0]=rp[cL]; w3[1]=m.x; w3[2]=m.y; w3[3]=m.z; w3[4]=m.w; w3[5]=rp[cR];
    }

    // ---- 3x3 min/max pools: triple (w0,w1,w2) for row ly0, (w1,w2,w3) for ly0+1
    float vmax0[4], vmin0[4], vmax1[4], vmin1[4];
    {
        float cmaxA[6], cminA[6], cmaxB[6], cminB[6];
        #pragma unroll
        for (int j = 0; j < 6; ++j) {
            float p12x = fmaxf(w1[j], w2[j]);
            float p12n = fminf(w1[j], w2[j]);
            cmaxA[j] = fmaxf(p12x, w0[j]);
            cminA[j] = fminf(p12n, w0[j]);
            cmaxB[j] = fmaxf(p12x, w3[j]);
            cminB[j] = fminf(p12n, w3[j]);
        }
        #pragma unroll
        for (int p = 0; p < 4; ++p) {
            vmax0[p] = fmaxf(fmaxf(cmaxA[p], cmaxA[p+1]), cmaxA[p+2]);
            vmin0[p] = fminf(fminf(cminA[p], cminA[p+1]), cminA[p+2]);
            vmax1[p] = fmaxf(fmaxf(cmaxB[p], cmaxB[p+1]), cmaxB[p+2]);
            vmin1[p] = fminf(fminf(cminB[p], cminB[p+1]), cminB[p+2]);
        }
    }

    // ---- x-grid constants per output-column parity (exact reference op order)
    float wx_[2]; bool dxm1_[2];
    #pragma unroll
    for (int par = 0; par < 2; ++par) {
        int ox = 8 * tx + par;
        float xs = (2.0f * (float)ox + 1.0f) / (float)WO_ - 1.0f;
        float gx = xs + 2.0f * (0.5f - jx) / (float)W_;
        float ix = ((gx + 1.0f) * (float)W_ - 1.0f) / 2.0f;
        float x0f = floorf(ix);
        wx_[par]   = ix - x0f;
        dxm1_[par] = ((int)x0f < lx0);   // x0 = m-1 (window shift) vs m
    }
    f32x2 wx2 = { wx_[0], wx_[1] };

    size_t base = (size_t)nc * ((size_t)HO_ * WO_);

    #pragma unroll
    for (int ory = 0; ory < 4; ++ory) {
        const int half = ory >> 1;        // which low-res row of the pair
        int lr = ly0 + half;
        int oy = 4 * ly2 + ory;
        float ysv = (2.0f * (float)oy + 1.0f) / (float)HO_ - 1.0f;
        float gy = ysv + 2.0f * (0.5f - jy) / (float)H_;
        float iy = ((gy + 1.0f) * (float)H_ - 1.0f) / 2.0f;
        float y0f = floorf(iy);
        float wy  = iy - y0f;
        bool up = ((int)y0f < lr);   // y0 row = lr-1 else lr

        // y-blend first; candidate rows are static per ory-half
        float brow[6];
        #pragma unroll
        for (int j = 0; j < 6; ++j) {
            float t0, t1;
            if (half == 0) { t0 = up ? w0[j] : w1[j]; t1 = up ? w1[j] : w2[j]; }
            else           { t0 = up ? w1[j] : w2[j]; t1 = up ? w2[j] : w3[j]; }
            brow[j] = t0 + wy * (t1 - t0);
        }
        // parity-shifted 5-wide views: s[j] = brow[j + (dm ? 0 : 1)]
        float s0[5], s1[5];
        #pragma unroll
        for (int j = 0; j < 5; ++j) {
            s0[j] = dxm1_[0] ? brow[j] : brow[j + 1];
            s1[j] = dxm1_[1] ? brow[j] : brow[j + 1];
        }

        bool rowb = ((ory & 1) == bjy);
        float res[8];
        #pragma unroll
        for (int bcol = 0; bcol < 4; ++bcol) {
            f32x2 v0 = { s0[bcol],     s1[bcol]     };
            f32x2 v1 = { s0[bcol + 1], s1[bcol + 1] };
            f32x2 bil = v0 + wx2 * (v1 - v0);
            float vx = (half == 0) ? vmax0[bcol] : vmax1[bcol];
            float vn = (half == 0) ? vmin0[bcol] : vmin1[bcol];
            f32x2 mx = { vx, vx };
            f32x2 mn = { vn, vn };
            f32x2 h  = __builtin_elementwise_max(mn, __builtin_elementwise_min(mx, bil));
            float zv = zcoin ? ((half == 0) ? w1[bcol + 1] : w2[bcol + 1]) : 0.0f;
            res[2*bcol + 0] = (rowb && (bjx == 0)) ? (0.1f * zv + (1.0f - 0.1f) * h.x) : h.x;
            res[2*bcol + 1] = (rowb && (bjx == 1)) ? (0.1f * zv + (1.0f - 0.1f) * h.y) : h.y;
        }

        size_t off = base + (size_t)oy * WO_ + (size_t)8 * tx;
        if ((long long)(off + 8) <= out_elems) {   // defensive: never write OOB
            f32x4 lo = { res[0], res[1], res[2], res[3] };
            f32x4 hi = { res[4], res[5], res[6], res[7] };
            *(f32x4*)(out + off)     = lo;
            *(f32x4*)(out + off + 4) = hi;
        }
    }
}

extern "C" void kernel_launch(void* const* d_in, const int* in_sizes, int n_in,
                              void* d_out, int out_size, void* d_ws, size_t ws_size,
                              hipStream_t stream) {
    const float* frame  = (const float*)d_in[0];
    const float* jitter = (const float*)d_in[1];
    float* out = (float*)d_out;

    const int total = N_ * C_ * (H_ / 2) * (W_ / 4);   // 777,600 threads, 32 px each
    const int block = 256;
    const int grid  = (total + block - 1) / block;      // 3038 blocks
    taa_fused_kernel<<<grid, block, 0, stream>>>(frame, jitter, out,
                                                 total, grid, (long long)out_size);
}